// Round 4
// baseline (35.312 us; speedup 1.0000x reference)
//
#include <hip/hip_runtime.h>
#include <math.h>

// Gaussian splat forward: N gaussians -> res x res image (res=256, N=1024).
//
// Stage 1 (gs_prep): per-gaussian quat->R, cov3d, project, invert, bbox.
// Expand quadratic about the pixel basis (log2-domain):
//   pw*log2e + log2(op) = c0*X^2 + c1*Y^2 + c2*XY + c3*X + c4*Y + c5
// so raster does acc += exp2(6-term fma chain).  The tile mask swaps c5 for
// -inf (exp2 -> 0) -- branchless and NaN-free (no inf*0 factorization).
// Extra leading blocks zero d_out so no separate memset launch is needed.
//
// Stage 2 (gs_raster): one block per 16x16 pixel tile x 128-gaussian chunk.
// All coefficients are BLOCK-UNIFORM -> scalar s_load_dwordx4; tile-mask test
// and c5/-inf select are SALU (parallel pipe). Inner loop has ZERO LDS/VMEM
// vector traffic: ~7 full-rate VALU + 1 exp2 per pixel-gaussian pair.

#define TILE 16
#define GCHUNK 128

__global__ __launch_bounds__(256) void gs_prep(
    const float* __restrict__ xyz, const float* __restrict__ scaling,
    const float* __restrict__ rotation, const float* __restrict__ opacity,
    const float* __restrict__ rot,
    float4* __restrict__ W, float* __restrict__ out,
    int N, int Npad, int res, int nt, int zeroBlocks)
{
    int bx = blockIdx.x;
    if (bx < zeroBlocks) {
        int idx = (bx * 256 + threadIdx.x) * 4;
        if (idx < res * res) *(float4*)(out + idx) = make_float4(0.f, 0.f, 0.f, 0.f);
        return;
    }
    int n = (bx - zeroBlocks) * 256 + threadIdx.x;
    if (n >= Npad) return;
    if (n >= N) {   // pad entries: zero masks -> c5eff=-inf -> exp2->0
        W[2*n]   = make_float4(0.f, 0.f, 0.f, 0.f);
        W[2*n+1] = make_float4(0.f, 0.f, 0.f, 0.f);
        return;
    }

    float resf = (float)res;

    // quaternion -> rotation matrix (reference normalizes first)
    float qr = rotation[4*n+0], qx = rotation[4*n+1];
    float qy = rotation[4*n+2], qz = rotation[4*n+3];
    float inv = 1.0f / sqrtf(qr*qr + qx*qx + qy*qy + qz*qz);
    float r = qr*inv, x = qx*inv, y = qy*inv, z = qz*inv;

    float R00 = 1.f - 2.f*(y*y + z*z), R01 = 2.f*(x*y - r*z), R02 = 2.f*(x*z + r*y);
    float R10 = 2.f*(x*y + r*z), R11 = 1.f - 2.f*(x*x + z*z), R12 = 2.f*(y*z - r*x);
    float R20 = 2.f*(x*z - r*y), R21 = 2.f*(y*z + r*x), R22 = 1.f - 2.f*(x*x + y*y);

    float s0 = scaling[3*n+0], s1 = scaling[3*n+1], s2 = scaling[3*n+2];
    float L00 = R00*s0, L01 = R01*s1, L02 = R02*s2;
    float L10 = R10*s0, L11 = R11*s1, L12 = R12*s2;
    float L20 = R20*s0, L21 = R21*s1, L22 = R22*s2;

    float a00 = resf*rot[0], a01 = resf*rot[1], a02 = resf*rot[2];
    float a10 = resf*rot[3], a11 = resf*rot[4], a12 = resf*rot[5];
    float b00 = a00*L00 + a01*L10 + a02*L20;
    float b01 = a00*L01 + a01*L11 + a02*L21;
    float b02 = a00*L02 + a01*L12 + a02*L22;
    float b10 = a10*L00 + a11*L10 + a12*L20;
    float b11 = a10*L01 + a11*L11 + a12*L21;
    float b12 = a10*L02 + a11*L12 + a12*L22;
    float c00 = b00*b00 + b01*b01 + b02*b02;
    float c01 = b00*b10 + b01*b11 + b02*b12;   // == c10
    float c11 = b10*b10 + b11*b11 + b12*b12;

    float det = c00*c11 - c01*c01;
    float mid = 0.5f*(c00 + c11);
    float sq  = sqrtf(fmaxf(mid*mid - det, 0.1f));
    float lam = fmaxf(mid + sq, mid - sq);
    float radii = ceilf(3.0f * sqrtf(lam));

    float mx = xyz[3*n+0] * (resf*0.5f);
    float my = xyz[3*n+1] * (resf*0.5f);
    float rminx = fminf(fmaxf(mx - radii, 0.f), resf - 1.f);
    float rmaxx = fminf(fmaxf(mx + radii, 0.f), resf - 1.f);
    float rminy = fminf(fmaxf(my - radii, 0.f), resf - 1.f);
    float rmaxy = fminf(fmaxf(my + radii, 0.f), resf - 1.f);

    // per-axis tile bitmasks (same float comparisons as the reference)
    unsigned mbx = 0u, mby = 0u;
    for (int t = 0; t < nt; ++t) {
        float t0 = (float)(t * TILE), t1 = t0 + (float)(TILE - 1);
        if (fminf(rmaxx, t1) > fmaxf(rminx, t0)) mbx |= (1u << t);
        if (fminf(rmaxy, t1) > fmaxf(rminy, t0)) mby |= (1u << t);
    }

    float idet = 1.0f / det;
    const float L2E = 1.44269504088896340736f;
    float A  = -0.5f * L2E * c11 * idet;
    float B  = -0.5f * L2E * c00 * idet;
    float Cc =         L2E * c01 * idet;

    float c3 = -2.f*A*mx - Cc*my;
    float c4 = -2.f*B*my - Cc*mx;
    float c5 = A*mx*mx + B*my*my + Cc*mx*my + log2f(opacity[n]);

    W[2*n]   = make_float4(A, B, Cc, c3);
    W[2*n+1] = make_float4(c4, c5, __uint_as_float(mbx), __uint_as_float(mby));
}

__global__ __launch_bounds__(256) void gs_raster(
    const float4* __restrict__ W, float* __restrict__ out,
    int res, int nt)
{
    int tid = threadIdx.x;
    int tX = blockIdx.x % nt, tY = blockIdx.x / nt;   // uniform (SGPR)
    const float4* Wp = W + (size_t)blockIdx.y * (GCHUNK * 2);

    int pxi = tX * TILE + (tid & (TILE - 1));
    int pyi = tY * TILE + (tid >> 4);  // TILE==16
    float X = (float)pxi - ((float)res * 0.5f - 0.5f);
    float Y = (float)pyi - ((float)res * 0.5f - 0.5f);
    float X2 = X * X, Y2 = Y * Y, XY = X * Y;

    float acc0 = 0.f, acc1 = 0.f, acc2 = 0.f, acc3 = 0.f;
    for (int i = 0; i < GCHUNK; i += 4) {
        // Uniform loads -> s_load; mask test + c5/-inf select -> SALU.
        // c5eff = -inf when masked: exp2 -> 0 exactly, never inf*0.
#define BODY(k, accv)                                                          \
        {                                                                      \
            float4 a = Wp[2*(i+(k))];                                          \
            float4 b = Wp[2*(i+(k))+1];                                        \
            unsigned mbx = __float_as_uint(b.z);                               \
            unsigned mby = __float_as_uint(b.w);                               \
            bool pass = ((mbx >> tX) & 1u) && ((mby >> tY) & 1u);              \
            float c5e = pass ? b.y : -INFINITY;                                \
            float q = fmaf(a.x, X2, fmaf(a.y, Y2, fmaf(a.z, XY,                \
                      fmaf(a.w, X, fmaf(b.x, Y, c5e)))));                      \
            accv += __builtin_amdgcn_exp2f(q);                                 \
        }
        BODY(0, acc0) BODY(1, acc1) BODY(2, acc2) BODY(3, acc3)
#undef BODY
    }
    atomicAdd(&out[pyi * res + pxi], (acc0 + acc1) + (acc2 + acc3));
}

extern "C" void kernel_launch(void* const* d_in, const int* in_sizes, int n_in,
                              void* d_out, int out_size, void* d_ws, size_t ws_size,
                              hipStream_t stream) {
    const float* xyz      = (const float*)d_in[0];
    const float* scaling  = (const float*)d_in[1];
    const float* rotation = (const float*)d_in[2];
    const float* opacity  = (const float*)d_in[3];
    const float* rot      = (const float*)d_in[4];
    int N   = in_sizes[0] / 3;
    int res = (int)(sqrt((double)out_size) + 0.5);
    int nt  = res / TILE;

    int ks   = (N + GCHUNK - 1) / GCHUNK;
    int Npad = ks * GCHUNK;

    float4* W  = (float4*)d_ws;           // Npad * 2 float4s
    float* out = (float*)d_out;

    int zeroBlocks  = (res * res + 1023) / 1024;
    int gaussBlocks = (Npad + 255) / 256;
    gs_prep<<<zeroBlocks + gaussBlocks, 256, 0, stream>>>(
        xyz, scaling, rotation, opacity, rot, W, out,
        N, Npad, res, nt, zeroBlocks);

    gs_raster<<<dim3(nt * nt, ks), 256, 0, stream>>>(W, out, res, nt);
}

// Round 5
// 23.460 us; speedup vs baseline: 1.5052x; 1.5052x over previous
//
#include <hip/hip_runtime.h>
#include <math.h>

// Gaussian splat forward: N gaussians -> res x res image (res=256, N=1024).
//
// Stage 1 (gs_prep): per-gaussian quat->R, cov3d, project, invert, bbox;
// expand quadratic in the pixel basis (log2 domain, opacity folded in):
//   q(X,Y) = A*X^2 + B*Y^2 + C*XY + c3*X + c4*Y + c5
// Emits P[n]=(A,B,C,c3), Q[n]=(c4,c5,maskx_bits,masky_bits). Leading blocks
// zero d_out (no separate memset launch).
//
// Stage 2 (gs_raster): block = 32x32 pixel tile x 64-gaussian chunk.
// The 32x32 tile is 4 reference 16x16 subtiles; wave w owns subtile w, so
// every LDS read is wave-uniform (pure broadcast, conflict-free). Each lane
// evaluates a 2x2 pixel quad -> 4 pixel evals per 24B of LDS data
// (b128+b64 = ~18cy LDS vs ~40cy VALU -> VALU-bound). Tile mask selected at
// stage time into per-subtile (c4, c5eff); masked -> c5eff=-inf -> exp2->0
// (never inf*0). acc += exp2(fma chain); 4 atomics per lane at the end.

#define TILE 16
#define BT 32
#define GCHUNK 64

__global__ __launch_bounds__(256) void gs_prep(
    const float* __restrict__ xyz, const float* __restrict__ scaling,
    const float* __restrict__ rotation, const float* __restrict__ opacity,
    const float* __restrict__ rot,
    float4* __restrict__ P, float4* __restrict__ Q, float* __restrict__ out,
    int N, int Npad, int res, int nt, int zeroBlocks)
{
    int bx = blockIdx.x;
    if (bx < zeroBlocks) {
        int idx = (bx * 256 + threadIdx.x) * 4;
        if (idx < res * res) *(float4*)(out + idx) = make_float4(0.f, 0.f, 0.f, 0.f);
        return;
    }
    int n = (bx - zeroBlocks) * 256 + threadIdx.x;
    if (n >= Npad) return;
    if (n >= N) {   // pad: zero masks -> c5eff=-inf -> exp2 -> 0, NaN-free
        P[n] = make_float4(0.f, 0.f, 0.f, 0.f);
        Q[n] = make_float4(0.f, 0.f, 0.f, 0.f);
        return;
    }

    float resf = (float)res;

    float qr = rotation[4*n+0], qx = rotation[4*n+1];
    float qy = rotation[4*n+2], qz = rotation[4*n+3];
    float inv = 1.0f / sqrtf(qr*qr + qx*qx + qy*qy + qz*qz);
    float r = qr*inv, x = qx*inv, y = qy*inv, z = qz*inv;

    float R00 = 1.f - 2.f*(y*y + z*z), R01 = 2.f*(x*y - r*z), R02 = 2.f*(x*z + r*y);
    float R10 = 2.f*(x*y + r*z), R11 = 1.f - 2.f*(x*x + z*z), R12 = 2.f*(y*z - r*x);
    float R20 = 2.f*(x*z - r*y), R21 = 2.f*(y*z + r*x), R22 = 1.f - 2.f*(x*x + y*y);

    float s0 = scaling[3*n+0], s1 = scaling[3*n+1], s2 = scaling[3*n+2];
    float L00 = R00*s0, L01 = R01*s1, L02 = R02*s2;
    float L10 = R10*s0, L11 = R11*s1, L12 = R12*s2;
    float L20 = R20*s0, L21 = R21*s1, L22 = R22*s2;

    float a00 = resf*rot[0], a01 = resf*rot[1], a02 = resf*rot[2];
    float a10 = resf*rot[3], a11 = resf*rot[4], a12 = resf*rot[5];
    float b00 = a00*L00 + a01*L10 + a02*L20;
    float b01 = a00*L01 + a01*L11 + a02*L21;
    float b02 = a00*L02 + a01*L12 + a02*L22;
    float b10 = a10*L00 + a11*L10 + a12*L20;
    float b11 = a10*L01 + a11*L11 + a12*L21;
    float b12 = a10*L02 + a11*L12 + a12*L22;
    float c00 = b00*b00 + b01*b01 + b02*b02;
    float c01 = b00*b10 + b01*b11 + b02*b12;   // == c10
    float c11 = b10*b10 + b11*b11 + b12*b12;

    float det = c00*c11 - c01*c01;
    float mid = 0.5f*(c00 + c11);
    float sq  = sqrtf(fmaxf(mid*mid - det, 0.1f));
    float lam = fmaxf(mid + sq, mid - sq);
    float radii = ceilf(3.0f * sqrtf(lam));

    float mx = xyz[3*n+0] * (resf*0.5f);
    float my = xyz[3*n+1] * (resf*0.5f);
    float rminx = fminf(fmaxf(mx - radii, 0.f), resf - 1.f);
    float rmaxx = fminf(fmaxf(mx + radii, 0.f), resf - 1.f);
    float rminy = fminf(fmaxf(my - radii, 0.f), resf - 1.f);
    float rmaxy = fminf(fmaxf(my + radii, 0.f), resf - 1.f);

    // per-axis 16px-tile bitmasks (same float compares as the reference)
    unsigned mbx = 0u, mby = 0u;
    for (int t = 0; t < nt; ++t) {
        float t0 = (float)(t * TILE), t1 = t0 + (float)(TILE - 1);
        if (fminf(rmaxx, t1) > fmaxf(rminx, t0)) mbx |= (1u << t);
        if (fminf(rmaxy, t1) > fmaxf(rminy, t0)) mby |= (1u << t);
    }

    float idet = 1.0f / det;
    const float L2E = 1.44269504088896340736f;
    float A  = -0.5f * L2E * c11 * idet;
    float B  = -0.5f * L2E * c00 * idet;
    float Cc =         L2E * c01 * idet;

    float c3 = -2.f*A*mx - Cc*my;
    float c4 = -2.f*B*my - Cc*mx;
    float c5 = A*mx*mx + B*my*my + Cc*mx*my + log2f(opacity[n]);

    P[n] = make_float4(A, B, Cc, c3);
    Q[n] = make_float4(c4, c5, __uint_as_float(mbx), __uint_as_float(mby));
}

__global__ __launch_bounds__(256) void gs_raster(
    const float4* __restrict__ P, const float4* __restrict__ Q,
    float* __restrict__ out, int res, int nbx)
{
    __shared__ float4 sP[GCHUNK];          // A,B,C,c3
    __shared__ float2 sQ[4][GCHUNK];       // per-subtile (c4, c5eff)

    int tid = threadIdx.x;
    int bTX = blockIdx.x % nbx, bTY = blockIdx.x / nbx;   // 32x32 tile
    int g0  = blockIdx.y * GCHUNK;

    if (tid < GCHUNK) {
        float4 p = P[g0 + tid];
        float4 q = Q[g0 + tid];
        unsigned mbx = __float_as_uint(q.z), mby = __float_as_uint(q.w);
        sP[tid] = p;
        int tx0 = bTX * 2, ty0 = bTY * 2;   // 16px-subtile indices
        #pragma unroll
        for (int s = 0; s < 4; ++s) {
            int sx = tx0 + (s & 1), sy = ty0 + (s >> 1);
            bool pass = ((mbx >> sx) & 1u) && ((mby >> sy) & 1u);
            sQ[s][tid] = make_float2(q.x, pass ? q.y : -INFINITY);
        }
    }
    __syncthreads();

    int w = tid >> 6, l = tid & 63;            // wave w owns subtile w
    int px0 = bTX * BT + (w & 1) * TILE + (l & 7) * 2;
    int py0 = bTY * BT + (w >> 1) * TILE + (l >> 3) * 2;
    float ctr = (float)res * 0.5f - 0.5f;
    float Xa = (float)px0 - ctr, Xb = Xa + 1.f;
    float Ya = (float)py0 - ctr, Yb = Ya + 1.f;
    float Xa2 = Xa*Xa, Xb2 = Xb*Xb, Ya2 = Ya*Ya, Yb2 = Yb*Yb;
    float XaYa = Xa*Ya, XbYa = Xb*Ya, XaYb = Xa*Yb, XbYb = Xb*Yb;

    const float2* __restrict__ sQw = sQ[w];    // wave-uniform row

    float acc00 = 0.f, acc10 = 0.f, acc01 = 0.f, acc11 = 0.f;
    #pragma unroll 4
    for (int i = 0; i < GCHUNK; ++i) {
        float4 p  = sP[i];                     // broadcast b128
        float2 qv = sQw[i];                    // broadcast b64
        float ux_a = fmaf(p.x, Xa2, p.w * Xa);
        float ux_b = fmaf(p.x, Xb2, p.w * Xb);
        float vy_a = fmaf(p.y, Ya2, fmaf(qv.x, Ya, qv.y));
        float vy_b = fmaf(p.y, Yb2, fmaf(qv.x, Yb, qv.y));
        acc00 += __builtin_amdgcn_exp2f(fmaf(p.z, XaYa, ux_a + vy_a));
        acc10 += __builtin_amdgcn_exp2f(fmaf(p.z, XbYa, ux_b + vy_a));
        acc01 += __builtin_amdgcn_exp2f(fmaf(p.z, XaYb, ux_a + vy_b));
        acc11 += __builtin_amdgcn_exp2f(fmaf(p.z, XbYb, ux_b + vy_b));
    }

    float* o = out + py0 * res + px0;
    atomicAdd(o,           acc00);
    atomicAdd(o + 1,       acc10);
    atomicAdd(o + res,     acc01);
    atomicAdd(o + res + 1, acc11);
}

extern "C" void kernel_launch(void* const* d_in, const int* in_sizes, int n_in,
                              void* d_out, int out_size, void* d_ws, size_t ws_size,
                              hipStream_t stream) {
    const float* xyz      = (const float*)d_in[0];
    const float* scaling  = (const float*)d_in[1];
    const float* rotation = (const float*)d_in[2];
    const float* opacity  = (const float*)d_in[3];
    const float* rot      = (const float*)d_in[4];
    int N   = in_sizes[0] / 3;
    int res = (int)(sqrt((double)out_size) + 0.5);
    int nt  = res / TILE;
    int nbx = res / BT;

    int ks   = (N + GCHUNK - 1) / GCHUNK;
    int Npad = ks * GCHUNK;

    float4* P  = (float4*)d_ws;            // Npad float4s
    float4* Q  = P + Npad;                 // Npad float4s
    float* out = (float*)d_out;

    int zeroBlocks  = (res * res + 1023) / 1024;
    int gaussBlocks = (Npad + 255) / 256;
    gs_prep<<<zeroBlocks + gaussBlocks, 256, 0, stream>>>(
        xyz, scaling, rotation, opacity, rot, P, Q, out,
        N, Npad, res, nt, zeroBlocks);

    gs_raster<<<dim3(nbx * nbx, ks), 256, 0, stream>>>(P, Q, out, res, nbx);
}